// Round 6
// baseline (519.106 us; speedup 1.0000x reference)
//
#include <hip/hip_runtime.h>
#include <math.h>

#define HW    65536      // 256*256
#define CHW   4194304    // 64*HW
#define SCALE 0.125f

typedef __attribute__((ext_vector_type(8)))  short          bf16x8;
typedef __attribute__((ext_vector_type(4)))  float          f32x4;
typedef __attribute__((ext_vector_type(2)))  unsigned short u16x2;
typedef __attribute__((ext_vector_type(4)))  unsigned short u16x4;
typedef __attribute__((ext_vector_type(8)))  unsigned short u16x8;

#define MFMA(a, b, c) __builtin_amdgcn_mfma_f32_16x16x32_bf16((a), (b), (c), 0, 0, 0)

__device__ __forceinline__ unsigned short f2b(float f) {
  unsigned u = __builtin_bit_cast(unsigned, f);
  return (unsigned short)((u + 0x7fffu + ((u >> 16) & 1u)) >> 16);
}

__device__ __forceinline__ bf16x8 ld_frag(const unsigned short* buf, int tile, int ks,
                                          int ln, int q) {
  return *(const bf16x8*)(buf + (16 * tile + ln) * 72 + 32 * ks + 8 * q);
}

__device__ __forceinline__ void st_cfrag(unsigned short* buf, const f32x4* acc, int wid,
                                         int ln, int q) {
#pragma unroll
  for (int nt = 0; nt < 4; nt++) {
    u16x4 w;
    w[0] = f2b(acc[nt][0]); w[1] = f2b(acc[nt][1]);
    w[2] = f2b(acc[nt][2]); w[3] = f2b(acc[nt][3]);
    *(u16x4*)(buf + (16 * nt + ln) * 72 + 16 * wid + 4 * q) = w;
  }
}

// ---------------- kernel 0: all fragment tables (113 blocks) ----------------
// blk<16 computes its slice of M = Qw^T Kw * SCALE inline (64-FMA dot per entry).
__global__ __launch_bounds__(256) void k_prep2(const float* __restrict__ qk_w,
                                               const float* __restrict__ v_w,
                                               const float* __restrict__ v_b,
                                               const float* __restrict__ out_w,
                                               const float* __restrict__ out_b,
                                               const float* __restrict__ ms1_w,
                                               const float* __restrict__ ms2_w,
                                               const float* __restrict__ fc1_w,
                                               const float* __restrict__ fc2_w,
                                               unsigned short* __restrict__ tabM,
                                               unsigned short* __restrict__ tabWv,
                                               unsigned short* __restrict__ tabWo,
                                               unsigned short* __restrict__ tabF1,
                                               unsigned short* __restrict__ tabF2,
                                               unsigned short* __restrict__ tabW1,
                                               unsigned short* __restrict__ tabW2,
                                               float* __restrict__ ob,
                                               float* __restrict__ gap,
                                               int build_conv) {
  int blk = blockIdx.x, t = threadIdx.x;
  if (blk < 16) {
    int idx = blk * 256 + t;
    int j = idx & 7, lin = idx >> 3;
    int lane = lin & 63, step = lin >> 6;
    int mt = step >> 1, ks = step & 1, q = lane >> 4, m = lane & 15;
    int k = 32 * ks + 8 * q + j;
    int v = 16 * mt + m;
    float s = 0.f;
    for (int a = 0; a < 64; a++)
      s = fmaf(qk_w[a * 64 + k], qk_w[(64 + a) * 64 + v], s);
    tabM[idx]  = f2b(s * SCALE);
    tabWv[idx] = f2b(v_w[v * 64 + k]);
    tabWo[idx] = f2b(out_w[v * 64 + k]);
  } else if (blk < 32) {
    if (!build_conv) return;
    int idx = (blk - 16) * 256 + t;
    int j = idx & 7, lin = idx >> 3;
    int lane = lin & 63, step = lin >> 6;
    int mt = step >> 1, ks = step & 1, q = lane >> 4, m = lane & 15;
    int k = 32 * ks + 8 * q + j;
    tabF1[idx] = f2b(fc1_w[(16 * mt + m) * 64 + k]);
    tabF2[idx] = f2b(fc2_w[(16 * mt + m) * 64 + k]);
  } else if (blk < 104) {
    if (!build_conv) return;
    int idx = (blk - 32) * 256 + t;                 // 0..18431
    int j = idx & 7, lane = (idx >> 3) & 63;
    int mt = (idx >> 9) & 1, ks = (idx >> 10) & 1, pos = idx >> 11;
    int o  = 16 * mt + (lane & 15);
    int ci = 32 * ks + 8 * (lane >> 4) + j;
    tabW1[idx] = f2b(ms1_w[(o * 64 + ci) * 9 + pos]);
  } else if (blk < 112) {
    if (!build_conv) return;
    int idx = (blk - 104) * 256 + t;                // 0..2047
    int j = idx & 7, lane = (idx >> 3) & 63, mt = idx >> 9;
    int o = 16 * mt + (lane & 15);
    int k = 8 * (lane >> 4) + j;
    tabW2[idx] = f2b(ms2_w[o * 32 + k]);
  } else {
    if (t < 64) {
      float s = out_b[t];
      for (int c = 0; c < 64; c++) s = fmaf(out_w[t * 64 + c], v_b[c], s);
      ob[t] = s;
    }
    for (int i = t; i < 512; i += 256) gap[i] = 0.f;
  }
}

// ---------------- kernel 0c: x -> channels-last bf16, fused GAP ----------------
__global__ __launch_bounds__(256) void k_tocl(const float* __restrict__ x,
                                              unsigned short* __restrict__ xcl,
                                              float* __restrict__ gap) {
  __shared__ unsigned short tile[16384];   // 256 pix x 64 ch (swizzled chunks)
  __shared__ float wsum[4][64];
  int t = threadIdx.x, lane = t & 63, wid = t >> 6;
  int pid0 = blockIdx.x * 256;
  int b = pid0 >> 16;
  const float* xp = x + (size_t)b * CHW + (pid0 & 65535) + t;
  int sw = t & 7;
#pragma unroll
  for (int c0 = 0; c0 < 8; c0++) {
    float v[8];
#pragma unroll
    for (int i = 0; i < 8; i++) v[i] = xp[(size_t)(c0 * 8 + i) * HW];
    u16x8 w;
#pragma unroll
    for (int i = 0; i < 8; i++) w[i] = f2b(v[i]);
    *(u16x8*)(tile + t * 64 + ((c0 ^ sw) << 3)) = w;
#pragma unroll
    for (int i = 0; i < 8; i++) {
      float s = v[i];
      s += __shfl_xor(s, 1, 64);  s += __shfl_xor(s, 2, 64);
      s += __shfl_xor(s, 4, 64);  s += __shfl_xor(s, 8, 64);
      s += __shfl_xor(s, 16, 64); s += __shfl_xor(s, 32, 64);
      if (lane == 0) wsum[wid][c0 * 8 + i] = s;
    }
  }
  __syncthreads();
  if (t < 64) {
    float g = (wsum[0][t] + wsum[1][t]) + (wsum[2][t] + wsum[3][t]);
    atomicAdd(&gap[b * 64 + t], g);
  }
  unsigned short* op = xcl + (size_t)pid0 * 64;
#pragma unroll
  for (int j = 0; j < 8; j++) {
    int p = j * 32 + (t >> 3);
    bf16x8 v = *(const bf16x8*)(tile + p * 64 + (((t & 7) ^ (p & 7)) << 3));
    *(bf16x8*)(op + j * 2048 + t * 8) = v;   // byte off = j*4096 + t*16: contiguous
  }
}

// ---------------- kernel 1 (fallback): global average pool per (b,c) -------------
__global__ __launch_bounds__(256) void k_gap(const float* __restrict__ x,
                                             float* __restrict__ gap) {
  int bc = blockIdx.x;
  const float4* p4 = (const float4*)(x + (size_t)bc * HW);
  float s = 0.f;
  for (int i = threadIdx.x; i < HW / 4; i += 256) {
    float4 v = p4[i];
    s += (v.x + v.y) + (v.z + v.w);
  }
#pragma unroll
  for (int off = 32; off > 0; off >>= 1) s += __shfl_down(s, off, 64);
  __shared__ float red[4];
  if ((threadIdx.x & 63) == 0) red[threadIdx.x >> 6] = s;
  __syncthreads();
  if (threadIdx.x == 0)
    gap[bc] = (red[0] + red[1] + red[2] + red[3]) * (1.f / 65536.f);
}

// ---------------- kernel 2 (fallback): SE gate ----------------
__global__ __launch_bounds__(256) void k_gate(const float* __restrict__ gap,
                                              const float* __restrict__ se1_w,
                                              const float* __restrict__ se1_b,
                                              const float* __restrict__ se2_w,
                                              const float* __restrict__ se2_b,
                                              float* __restrict__ gate) {
  __shared__ float se[32];
  int t = threadIdx.x;
  if (t < 32) {
    int b = t >> 2, j = t & 3;
    float s = se1_b[j];
    for (int c = 0; c < 64; c++) s = fmaf(gap[b * 64 + c], se1_w[j * 64 + c], s);
    se[t] = fmaxf(s, 0.f);
  }
  __syncthreads();
  for (int i = t; i < 512; i += 256) {
    int b = i >> 6, o = i & 63;
    float s = se2_b[o];
#pragma unroll
    for (int j = 0; j < 4; j++) s = fmaf(se[b * 4 + j], se2_w[o * 4 + j], s);
    gate[i] = 1.f / (1.f + expf(-s));
  }
}

// ---------------- kernel 3 (fast): MFMA conv, 512 threads (8 waves) ----------
__global__ __launch_bounds__(512) void k_ms_mfma(const float* __restrict__ x,
                                                 const unsigned short* __restrict__ xcl,
                                                 const unsigned short* __restrict__ tabW1,
                                                 const unsigned short* __restrict__ tabW2,
                                                 const float* __restrict__ b1,
                                                 const float* __restrict__ b2,
                                                 float* __restrict__ x1) {
  __shared__ unsigned short sX[324 * 72];  // 46656 B; relu buf aliased (256*40 halves)
  int b = blockIdx.z;
  int x0 = blockIdx.x * 16, y0 = blockIdx.y * 16;
  int t = threadIdx.x, lane = t & 63, wid = t >> 6;   // wid 0..7
  int q = lane >> 4, ln = lane & 15;

  for (int i = t; i < 2592; i += 512) {  // 324 pixels x 8 chan-octets
    int c8 = i & 7, pix = i >> 3;
    int yy = pix / 18, xx = pix - yy * 18;
    int gy = y0 + yy - 1, gx = x0 + xx - 1;
    bf16x8 v = {0, 0, 0, 0, 0, 0, 0, 0};
    if (gy >= 0 && gy < 256 && gx >= 0 && gx < 256)
      v = *(const bf16x8*)(xcl + ((size_t)((b << 16) + (gy << 8) + gx) << 6) + c8 * 8);
    *(bf16x8*)(sX + pix * 72 + c8 * 8) = v;
  }
  __syncthreads();

  f32x4 b1v0 = *(const f32x4*)(b1 + 4 * q);
  f32x4 b1v1 = *(const f32x4*)(b1 + 16 + 4 * q);
  f32x4 acc[2][2];
#pragma unroll
  for (int j = 0; j < 2; j++) { acc[j][0] = b1v0; acc[j][1] = b1v1; }

  for (int pos = 0; pos < 9; pos++) {
    int dy = pos / 3, dx = pos - dy * 3;
    bf16x8 A[2][2];
#pragma unroll
    for (int ks = 0; ks < 2; ks++)
#pragma unroll
      for (int mt = 0; mt < 2; mt++)
        A[ks][mt] = *(const bf16x8*)(tabW1 + ((((pos * 2 + ks) * 2 + mt) * 64 + lane) << 3));
#pragma unroll
    for (int j = 0; j < 2; j++) {
      int py = 2 * wid + j;
      int pix = (py + dy) * 18 + ln + dx;
#pragma unroll
      for (int ks = 0; ks < 2; ks++) {
        bf16x8 B = *(const bf16x8*)(sX + pix * 72 + 32 * ks + 8 * q);
        acc[j][0] = MFMA(A[ks][0], B, acc[j][0]);
        acc[j][1] = MFMA(A[ks][1], B, acc[j][1]);
      }
    }
  }
  __syncthreads();  // all conv reads of sX complete

  // relu -> [pix][cin32] pitch 40 halves (aliases sX)
#pragma unroll
  for (int j = 0; j < 2; j++) {
    int pixl = (2 * wid + j) * 16 + ln;
#pragma unroll
    for (int mt = 0; mt < 2; mt++) {
      u16x4 w;
#pragma unroll
      for (int r = 0; r < 4; r++) w[r] = f2b(fmaxf(acc[j][mt][r], 0.f));
      *(u16x4*)(sX + pixl * 40 + 16 * mt + 4 * q) = w;
    }
  }
  __syncthreads();

  bf16x8 A2[4];
#pragma unroll
  for (int mt = 0; mt < 4; mt++)
    A2[mt] = *(const bf16x8*)(tabW2 + ((mt * 64 + lane) << 3));
  f32x4 b2v[4];
#pragma unroll
  for (int mt = 0; mt < 4; mt++) b2v[mt] = *(const f32x4*)(b2 + 16 * mt + 4 * q);

  const f32x4 z4 = {0.f, 0.f, 0.f, 0.f};
#pragma unroll
  for (int j = 0; j < 2; j++) {
    int py = 2 * wid + j;
    bf16x8 B = *(const bf16x8*)(sX + (py * 16 + ln) * 40 + 8 * q);
    f32x4 acc2[4] = {z4, z4, z4, z4};
#pragma unroll
    for (int mt = 0; mt < 4; mt++) acc2[mt] = MFMA(A2[mt], B, acc2[mt]);
    size_t pbase = (size_t)b * CHW + (size_t)(y0 + py) * 256 + x0 + ln;
#pragma unroll
    for (int mt = 0; mt < 4; mt++)
#pragma unroll
      for (int r = 0; r < 4; r++) {
        int o = 16 * mt + 4 * q + r;
        size_t idx = pbase + (size_t)o * HW;
        x1[idx] = x[idx] + acc2[mt][r] + b2v[mt][r];
      }
  }
}

// ---------------- kernel 3 (fallback): scalar conv, same semantics ----------------
__global__ __launch_bounds__(256) void k_ms_scalar(const float* __restrict__ x,
                                                   const float* __restrict__ w1,
                                                   const float* __restrict__ b1,
                                                   const float* __restrict__ w2,
                                                   const float* __restrict__ b2,
                                                   float* __restrict__ x1) {
  int b = blockIdx.z;
  int x0 = blockIdx.x * 16, y0 = blockIdx.y * 16;
  int tx = threadIdx.x & 15, ty = threadIdx.x >> 4;
  __shared__ float xt[16 * 324];
  float acc[32];
#pragma unroll
  for (int o = 0; o < 32; o++) acc[o] = 0.f;
  const float* xb = x + (size_t)b * CHW;

  for (int cc = 0; cc < 64; cc += 16) {
    __syncthreads();
    for (int idx = threadIdx.x; idx < 16 * 324; idx += 256) {
      int ci = idx / 324;
      int rem = idx - ci * 324;
      int yy = rem / 18, xx = rem - yy * 18;
      int gy = y0 + yy - 1, gx = x0 + xx - 1;
      float v = 0.f;
      if (gy >= 0 && gy < 256 && gx >= 0 && gx < 256)
        v = xb[(size_t)(cc + ci) * HW + gy * 256 + gx];
      xt[idx] = v;
    }
    __syncthreads();
    for (int ci = 0; ci < 16; ci++) {
      float xv[9];
#pragma unroll
      for (int dy = 0; dy < 3; dy++)
#pragma unroll
        for (int dx = 0; dx < 3; dx++)
          xv[dy * 3 + dx] = xt[ci * 324 + (ty + dy) * 18 + tx + dx];
      const float* wp = w1 + (size_t)(cc + ci) * 9;
#pragma unroll
      for (int o = 0; o < 32; o++) {
        float s = acc[o];
#pragma unroll
        for (int k = 0; k < 9; k++) s = fmaf(xv[k], wp[o * 576 + k], s);
        acc[o] = s;
      }
    }
  }
  float r[32];
#pragma unroll
  for (int o = 0; o < 32; o++) r[o] = fmaxf(acc[o] + b1[o], 0.f);
  size_t pix = (size_t)(y0 + ty) * 256 + (x0 + tx);
  size_t base = (size_t)b * CHW + pix;
#pragma unroll 8
  for (int o = 0; o < 64; o++) {
    float s = b2[o];
#pragma unroll
    for (int i = 0; i < 32; i++) s = fmaf(r[i], w2[o * 32 + i], s);
    x1[base + (size_t)o * HW] = xb[(size_t)o * HW + pix] + s;
  }
}

// ---------------- kernel 4 (fast): attention + SE gate + LN + FFN, 2-buffer -------
// Two LDS half-buffers per window (mA, mB) instead of three: V overwrites the
// window tile in mA (dead after xa register load), O overwrites scores in mB,
// fc1 output overwrites V in mA. LDS 63->44KB => 3 blocks/CU. SE hidden layer is
// wave-parallel (shfl butterfly), not 4-thread-serial.
__global__ __launch_bounds__(512) void k_attn(const unsigned short* __restrict__ xcl,
                                              const unsigned short* __restrict__ tabM,
                                              const unsigned short* __restrict__ tabWv,
                                              const unsigned short* __restrict__ tabWo,
                                              const float* __restrict__ ob,
                                              const float* __restrict__ gap,
                                              const float* __restrict__ se1_w,
                                              const float* __restrict__ se1_b,
                                              const float* __restrict__ se2_w,
                                              const float* __restrict__ se2_b,
                                              const float* __restrict__ ln_g,
                                              const float* __restrict__ ln_b,
                                              const unsigned short* __restrict__ tabF1,
                                              const float* __restrict__ fc1_b,
                                              const unsigned short* __restrict__ tabF2,
                                              const float* __restrict__ fc2_b,
                                              float* __restrict__ x1) {
  __shared__ unsigned short sA[2][4608], sB[2][4608];
  __shared__ float red[2][256];
  __shared__ float pss[2][2][256];       // [wg][{s1,s2}][wl*64+tok]
  __shared__ float mus[2][64], rvs[2][64];
  __shared__ float seh[4];
  int n = blockIdx.x;                  // 4096 blocks
  int b = n >> 9, rem = n & 511;
  int wy = rem >> 4, wx2 = rem & 15;
  int t = threadIdx.x;
  int wg = t >> 8;                     // which window half
  int th = t & 255;
  int lane = th & 63, wl = th >> 6;    // role-wave within half
  int q = lane >> 4, ln = lane & 15;
  int wx = wx2 * 2 + wg;
  int pid0 = (b << 16) + ((wy * 8) << 8) + wx * 8;  // pixel id of window origin

  unsigned short* mA = sA[wg];
  unsigned short* mB = sB[wg];
  float* mred = red[wg];

  // ---- load window from xcl: fully coalesced ----
  {
    const unsigned short* xw = xcl + ((size_t)pid0 << 6);
#pragma unroll
    for (int it = 0; it < 2; it++) {
      int id = th + 256 * it;          // 0..511
      int tok = id >> 3, c8 = id & 7;
      int off = ((tok >> 3) << 8) + (tok & 7);  // row*256 + col
      bf16x8 v = *(const bf16x8*)(xw + ((size_t)off << 6) + c8 * 8);
      *(bf16x8*)(mA + tok * 72 + c8 * 8) = v;
    }
  }

  // ---- prefetch x1 residual (x + ms, written by k_ms) ----
  float* x1b = x1 + (size_t)b * CHW + (size_t)(wy * 8) * 256 + wx * 8;
  float xv[4][4];
#pragma unroll
  for (int r = 0; r < 4; r++) {
    int cho = 16 * wl + 4 * q + r;
#pragma unroll
    for (int nt = 0; nt < 4; nt++) {
      int tok = 16 * nt + ln;
      xv[nt][r] = x1b[(size_t)cho * HW + (size_t)(tok >> 3) * 256 + (tok & 7)];
    }
  }

  // ---- SE hidden layer: wave 0, lane-parallel over 64 channels ----
  if (t < 64) {
    float gv = gap[b * 64 + t] * (1.f / 65536.f);
#pragma unroll
    for (int j = 0; j < 4; j++) {
      float p = gv * se1_w[j * 64 + t];
      p += __shfl_xor(p, 1, 64);  p += __shfl_xor(p, 2, 64);
      p += __shfl_xor(p, 4, 64);  p += __shfl_xor(p, 8, 64);
      p += __shfl_xor(p, 16, 64); p += __shfl_xor(p, 32, 64);
      if (t == 0) seh[j] = fmaxf(p + se1_b[j], 0.f);
    }
  }
  __syncthreads();                                          // B1

  const f32x4 z4 = {0.f, 0.f, 0.f, 0.f};

  // ---- phase 1: T = M . X^T -> mB ----
  {
    bf16x8 a0 = *(const bf16x8*)(tabM + ((wl * 2 + 0) * 64 + lane) * 8);
    bf16x8 a1 = *(const bf16x8*)(tabM + ((wl * 2 + 1) * 64 + lane) * 8);
    f32x4 acc[4] = {z4, z4, z4, z4};
#pragma unroll
    for (int nt = 0; nt < 4; nt++) {
      bf16x8 b0 = ld_frag(mA, nt, 0, ln, q);
      bf16x8 b1 = ld_frag(mA, nt, 1, ln, q);
      acc[nt] = MFMA(a0, b0, acc[nt]);
      acc[nt] = MFMA(a1, b1, acc[nt]);
    }
    st_cfrag(mB, acc, wl, ln, q);
  }
  __syncthreads();                                          // B2

  // ---- phase 2: S = X.T^T, V = X.Wv^T ----
  f32x4 accS[4] = {z4, z4, z4, z4}, accV[4] = {z4, z4, z4, z4};
  {
    bf16x8 xa0 = ld_frag(mA, wl, 0, ln, q);
    bf16x8 xa1 = ld_frag(mA, wl, 1, ln, q);
#pragma unroll
    for (int nt = 0; nt < 4; nt++) {
      bf16x8 tb0 = ld_frag(mB, nt, 0, ln, q);
      bf16x8 tb1 = ld_frag(mB, nt, 1, ln, q);
      accS[nt] = MFMA(xa0, tb0, accS[nt]);
      accS[nt] = MFMA(xa1, tb1, accS[nt]);
      bf16x8 vb0 = *(const bf16x8*)(tabWv + ((nt * 2 + 0) * 64 + lane) * 8);
      bf16x8 vb1 = *(const bf16x8*)(tabWv + ((nt * 2 + 1) * 64 + lane) * 8);
      accV[nt] = MFMA(xa0, vb0, accV[nt]);
      accV[nt] = MFMA(xa1, vb1, accV[nt]);
    }
  }

  // softmax exp + per-row partial sums (registers only)
  float psum[4];
#pragma unroll
  for (int nt = 0; nt < 4; nt++) {
    f32x4 e;
    e[0] = __expf(accS[nt][0]); e[1] = __expf(accS[nt][1]);
    e[2] = __expf(accS[nt][2]); e[3] = __expf(accS[nt][3]);
    accS[nt] = e;
    float s = (e[0] + e[1]) + (e[2] + e[3]);
    s += __shfl_xor(s, 16, 64);
    s += __shfl_xor(s, 32, 64);
    psum[nt] = s;
  }
  __syncthreads();                     // B3: all mA(X)/mB(T) reads complete

  st_cfrag(mA, accV, wl, ln, q);       // V overwrites window tile
  if (lane < 16) {
#pragma unroll
    for (int nt = 0; nt < 4; nt++) mred[wl * 64 + nt * 16 + ln] = psum[nt];
  }
  __syncthreads();                                          // B4

  // ---- normalize P -> mB (overwrites T) ----
  {
    f32x4 accP[4];
#pragma unroll
    for (int nt = 0; nt < 4; nt++) {
      int col = nt * 16 + ln;
      float tot = (mred[col] + mred[64 + col]) + (mred[128 + col] + mred[192 + col]);
      float inv = 1.f / tot;
      accP[nt][0] = accS[nt][0] * inv; accP[nt][1] = accS[nt][1] * inv;
      accP[nt][2] = accS[nt][2] * inv; accP[nt][3] = accS[nt][3] * inv;
    }
    st_cfrag(mB, accP, wl, ln, q);
  }
  __syncthreads();                                          // B5

  // ---- PV: O = V . P ----
  f32x4 accO[4] = {z4, z4, z4, z4};
  {
    bf16x8 va0 = ld_frag(mA, wl, 0, ln, q);
    bf16x8 va1 = ld_frag(mA, wl, 1, ln, q);
#pragma unroll
    for (int nt = 0; nt < 4; nt++) {
      bf16x8 pb0 = ld_frag(mB, nt, 0, ln, q);
      bf16x8 pb1 = ld_frag(mB, nt, 1, ln, q);
      accO[nt] = MFMA(va0, pb0, accO[nt]);
      accO[nt] = MFMA(va1, pb1, accO[nt]);
    }
  }
  __syncthreads();                     // B6: all mB(P) reads complete
  st_cfrag(mB, accO, wl, ln, q);       // O overwrites P
  __syncthreads();                                          // B7

  // ---- out-proj ----
  f32x4 accY[4] = {z4, z4, z4, z4};
  {
    bf16x8 wa0 = *(const bf16x8*)(tabWo + ((wl * 2 + 0) * 64 + lane) * 8);
    bf16x8 wa1 = *(const bf16x8*)(tabWo + ((wl * 2 + 1) * 64 + lane) * 8);
#pragma unroll
    for (int nt = 0; nt < 4; nt++) {
      bf16x8 ob0 = ld_frag(mB, nt, 0, ln, q);
      bf16x8 ob1 = ld_frag(mB, nt, 1, ln, q);
      accY[nt] = MFMA(wa0, ob0, accY[nt]);
      accY[nt] = MFMA(wa1, ob1, accY[nt]);
    }
  }

  // ---- x1 = x + ms + attn*gate + obg (gate from seh) ----
#pragma unroll
  for (int r = 0; r < 4; r++) {
    int cho = 16 * wl + 4 * q + r;
    f32x4 w2v = *(const f32x4*)(se2_w + cho * 4);
    float sg = se2_b[cho] + seh[0] * w2v[0] + seh[1] * w2v[1] +
               seh[2] * w2v[2] + seh[3] * w2v[3];
    float gv = 1.f / (1.f + expf(-sg));
    float obg = ob[cho] * gv;
#pragma unroll
    for (int nt = 0; nt < 4; nt++)
      xv[nt][r] = xv[nt][r] + accY[nt][r] * gv + obg;
  }

  // ---- LN partials: shfl over q, store per (wl, tok) ----
#pragma unroll
  for (int nt = 0; nt < 4; nt++) {
    float s1 = (xv[nt][0] + xv[nt][1]) + (xv[nt][2] + xv[nt][3]);
    float s2 = fmaf(xv[nt][0], xv[nt][0], xv[nt][1] * xv[nt][1]) +
               fmaf(xv[nt][2], xv[nt][2], xv[nt][3] * xv[nt][3]);
    s1 += __shfl_xor(s1, 16, 64); s1 += __shfl_xor(s1, 32, 64);
    s2 += __shfl_xor(s2, 16, 64); s2 += __shfl_xor(s2, 32, 64);
    if (lane < 16) {
      pss[wg][0][wl * 64 + 16 * nt + ln] = s1;
      pss[wg][1][wl * 64 + 16 * nt + ln] = s2;
    }
  }
  __syncthreads();                                          // B8

  if (wl == 0) {
    int tok = lane;
    float s1 = (pss[wg][0][tok] + pss[wg][0][64 + tok]) +
               (pss[wg][0][128 + tok] + pss[wg][0][192 + tok]);
    float s2 = (pss[wg][1][tok] + pss[wg][1][64 + tok]) +
               (pss[wg][1][128 + tok] + pss[wg][1][192 + tok]);
    float mu = s1 * (1.f / 64.f);
    float m2 = s2 * (1.f / 64.f);
    mus[wg][tok] = mu;
    rvs[wg][tok] = rsqrtf(m2 - mu * mu + 1e-5f);
  }
  __syncthreads();                                          // B9

  // ---- normalized bf16 tile -> mB (overwrites O; out-proj reads done) ----
  {
    f32x4 lg = *(const f32x4*)(ln_g + 16 * wl + 4 * q);
    f32x4 lb = *(const f32x4*)(ln_b + 16 * wl + 4 * q);
#pragma unroll
    for (int nt = 0; nt < 4; nt++) {
      int tok = 16 * nt + ln;
      float mu = mus[wg][tok], rinv = rvs[wg][tok];
      u16x4 w;
#pragma unroll
      for (int r = 0; r < 4; r++)
        w[r] = f2b((xv[nt][r] - mu) * rinv * lg[r] + lb[r]);
      *(u16x4*)(mB + tok * 72 + 16 * wl + 4 * q) = w;
    }
  }
  __syncthreads();                                          // B10

  // ---- fc1 + GELU -> mA (overwrites V; PV reads done) ----
  f32x4 accF[4];
  {
    bf16x8 a0 = *(const bf16x8*)(tabF1 + ((wl * 2 + 0) * 64 + lane) * 8);
    bf16x8 a1 = *(const bf16x8*)(tabF1 + ((wl * 2 + 1) * 64 + lane) * 8);
    f32x4 bias1 = *(const f32x4*)(fc1_b + 16 * wl + 4 * q);
#pragma unroll
    for (int nt = 0; nt < 4; nt++) {
      accF[nt] = bias1;
      bf16x8 b0 = ld_frag(mB, nt, 0, ln, q);
      bf16x8 b1 = ld_frag(mB, nt, 1, ln, q);
      accF[nt] = MFMA(a0, b0, accF[nt]);
      accF[nt] = MFMA(a1, b1, accF[nt]);
    }
  }
#pragma unroll
  for (int nt = 0; nt < 4; nt++)
#pragma unroll
    for (int r = 0; r < 4; r++) {
      float z = accF[nt][r];
      float u = 0.7978845608028654f * (z + 0.044715f * z * z * z);
      float e = __expf(-2.f * u);
      accF[nt][r] = z * __builtin_amdgcn_rcpf(1.f + e);
    }
  st_cfrag(mA, accF, wl, ln, q);
  __syncthreads();                                          // B11

  // ---- fc2 + residual write: out = x1 + ffn ----
  {
    bf16x8 c0 = *(const bf16x8*)(tabF2 + ((wl * 2 + 0) * 64 + lane) * 8);
    bf16x8 c1 = *(const bf16x8*)(tabF2 + ((wl * 2 + 1) * 64 + lane) * 8);
    f32x4 bias2 = *(const f32x4*)(fc2_b + 16 * wl + 4 * q);
#pragma unroll
    for (int nt = 0; nt < 4; nt++) {
      f32x4 a2 = bias2;
      bf16x8 b0 = ld_frag(mA, nt, 0, ln, q);
      bf16x8 b1 = ld_frag(mA, nt, 1, ln, q);
      a2 = MFMA(c0, b0, a2);
      a2 = MFMA(c1, b1, a2);
      int tok = 16 * nt + ln;
      size_t rowoff = (size_t)(tok >> 3) * 256 + (tok & 7);
#pragma unroll
      for (int r = 0; r < 4; r++) {
        int cho = 16 * wl + 4 * q + r;
        x1b[(size_t)cho * HW + rowoff] = xv[nt][r] + a2[r];
      }
    }
  }
}

// ---------------- kernel 4 (fallback): original fp32-input attention ----------------
__global__ __launch_bounds__(256) void k_attn_x(const float* __restrict__ x,
                                                const unsigned short* __restrict__ tabM,
                                                const unsigned short* __restrict__ tabWv,
                                                const unsigned short* __restrict__ tabWo,
                                                const float* __restrict__ ob,
                                                const float* __restrict__ gate,
                                                float* __restrict__ x1) {
  __shared__ unsigned short sA[4608], sB[4608], sC[4608];
  __shared__ float red[256];
  int n = blockIdx.x;
  int b = n >> 10, wy = (n >> 5) & 31, wx = n & 31;
  int t = threadIdx.x, lane = t & 63, wid = t >> 6;
  int q = lane >> 4, ln = lane & 15;
  const float* xb = x + (size_t)b * CHW + (size_t)(wy * 8) * 256 + wx * 8;

  {
    int p = t & 31, tg = t >> 5;
    const float* r0 = xb + (size_t)(2 * p) * HW + tg * 256;
    const float* r1 = r0 + HW;
    float a0[8], a1[8];
    *(float4*)&a0[0] = *(const float4*)r0;
    *(float4*)&a0[4] = *(const float4*)(r0 + 4);
    *(float4*)&a1[0] = *(const float4*)r1;
    *(float4*)&a1[4] = *(const float4*)(r1 + 4);
#pragma unroll
    for (int k2 = 0; k2 < 8; k2++) {
      u16x2 w; w[0] = f2b(a0[k2]); w[1] = f2b(a1[k2]);
      *(u16x2*)(sA + (tg * 8 + k2) * 72 + 2 * p) = w;
    }
  }
  __syncthreads();

  const f32x4 z4 = {0.f, 0.f, 0.f, 0.f};

  {
    bf16x8 a0 = *(const bf16x8*)(tabM + ((wid * 2 + 0) * 64 + lane) * 8);
    bf16x8 a1 = *(const bf16x8*)(tabM + ((wid * 2 + 1) * 64 + lane) * 8);
    f32x4 acc[4] = {z4, z4, z4, z4};
#pragma unroll
    for (int nt = 0; nt < 4; nt++) {
      bf16x8 b0 = ld_frag(sA, nt, 0, ln, q);
      bf16x8 b1 = ld_frag(sA, nt, 1, ln, q);
      acc[nt] = MFMA(a0, b0, acc[nt]);
      acc[nt] = MFMA(a1, b1, acc[nt]);
    }
    st_cfrag(sB, acc, wid, ln, q);
  }
  __syncthreads();

  f32x4 accS[4] = {z4, z4, z4, z4}, accV[4] = {z4, z4, z4, z4};
  {
    bf16x8 xa0 = ld_frag(sA, wid, 0, ln, q);
    bf16x8 xa1 = ld_frag(sA, wid, 1, ln, q);
#pragma unroll
    for (int nt = 0; nt < 4; nt++) {
      bf16x8 tb0 = ld_frag(sB, nt, 0, ln, q);
      bf16x8 tb1 = ld_frag(sB, nt, 1, ln, q);
      accS[nt] = MFMA(xa0, tb0, accS[nt]);
      accS[nt] = MFMA(xa1, tb1, accS[nt]);
      bf16x8 vb0 = *(const bf16x8*)(tabWv + ((nt * 2 + 0) * 64 + lane) * 8);
      bf16x8 vb1 = *(const bf16x8*)(tabWv + ((nt * 2 + 1) * 64 + lane) * 8);
      accV[nt] = MFMA(xa0, vb0, accV[nt]);
      accV[nt] = MFMA(xa1, vb1, accV[nt]);
    }
  }
  st_cfrag(sC, accV, wid, ln, q);

  float psum[4];
#pragma unroll
  for (int nt = 0; nt < 4; nt++) {
    f32x4 e;
    e[0] = __expf(accS[nt][0]); e[1] = __expf(accS[nt][1]);
    e[2] = __expf(accS[nt][2]); e[3] = __expf(accS[nt][3]);
    accS[nt] = e;
    float s = (e[0] + e[1]) + (e[2] + e[3]);
    s += __shfl_xor(s, 16, 64);
    s += __shfl_xor(s, 32, 64);
    psum[nt] = s;
  }
  if (lane < 16) {
#pragma unroll
    for (int nt = 0; nt < 4; nt++) red[wid * 64 + nt * 16 + ln] = psum[nt];
  }
  __syncthreads();

  {
    f32x4 accP[4];
#pragma unroll
    for (int nt = 0; nt < 4; nt++) {
      int col = nt * 16 + ln;
      float tot = (red[col] + red[64 + col]) + (red[128 + col] + red[192 + col]);
      float inv = 1.f / tot;
      accP[nt][0] = accS[nt][0] * inv; accP[nt][1] = accS[nt][1] * inv;
      accP[nt][2] = accS[nt][2] * inv; accP[nt][3] = accS[nt][3] * inv;
    }
    st_cfrag(sB, accP, wid, ln, q);
  }
  __syncthreads();

  f32x4 accO[4] = {z4, z4, z4, z4};
  {
    bf16x8 va0 = ld_frag(sC, wid, 0, ln, q);
    bf16x8 va1 = ld_frag(sC, wid, 1, ln, q);
#pragma unroll
    for (int nt = 0; nt < 4; nt++) {
      bf16x8 pb0 = ld_frag(sB, nt, 0, ln, q);
      bf16x8 pb1 = ld_frag(sB, nt, 1, ln, q);
      accO[nt] = MFMA(va0, pb0, accO[nt]);
      accO[nt] = MFMA(va1, pb1, accO[nt]);
    }
  }
  st_cfrag(sA, accO, wid, ln, q);
  __syncthreads();

  f32x4 accY[4] = {z4, z4, z4, z4};
  {
    bf16x8 wa0 = *(const bf16x8*)(tabWo + ((wid * 2 + 0) * 64 + lane) * 8);
    bf16x8 wa1 = *(const bf16x8*)(tabWo + ((wid * 2 + 1) * 64 + lane) * 8);
#pragma unroll
    for (int nt = 0; nt < 4; nt++) {
      bf16x8 ob0 = ld_frag(sA, nt, 0, ln, q);
      bf16x8 ob1 = ld_frag(sA, nt, 1, ln, q);
      accY[nt] = MFMA(wa0, ob0, accY[nt]);
      accY[nt] = MFMA(wa1, ob1, accY[nt]);
    }
  }

  float* x1b = x1 + (size_t)b * CHW + (size_t)(wy * 8) * 256 + wx * 8;
#pragma unroll
  for (int r = 0; r < 4; r++) {
    int cho = 16 * wid + 4 * q + r;
    float gv = gate[b * 64 + cho];
    float obg = ob[cho] * gv;
#pragma unroll
    for (int nt = 0; nt < 4; nt++) {
      int tok = 16 * nt + ln;
      size_t off = (size_t)cho * HW + (size_t)(tok >> 3) * 256 + (tok & 7);
      x1b[off] += accY[nt][r] * gv + obg;
    }
  }
}

// ---------------- kernel 5 (fallback): scalar FFN ----------------
__global__ __launch_bounds__(256) void k_ffn_scalar(float* __restrict__ x1out,
                                                    const float* __restrict__ ln_g,
                                                    const float* __restrict__ ln_b,
                                                    const float* __restrict__ fc1_w,
                                                    const float* __restrict__ fc1_b,
                                                    const float* __restrict__ fc2_w,
                                                    const float* __restrict__ fc2_b) {
  __shared__ float xt[4096], tn[4096], hs[4096], ps[512];
  int n = blockIdx.x;
  int b = n >> 10;
  int rem = n & 1023;
  int y = rem >> 2;
  int x0 = (rem & 3) * 64;
  int t = threadIdx.x, p = t & 63;
  int g = __builtin_amdgcn_readfirstlane(t >> 6);
  size_t base = (size_t)b * CHW + (size_t)y * 256 + x0;

  for (int idx = t; idx < 4096; idx += 256) {
    int c = idx >> 6, pp = idx & 63;
    xt[idx] = x1out[base + (size_t)c * HW + pp];
  }
  __syncthreads();

  float s1 = 0.f, s2 = 0.f;
#pragma unroll
  for (int i = 0; i < 16; i++) {
    float v = xt[(g * 16 + i) * 64 + p];
    s1 += v;
    s2 = fmaf(v, v, s2);
  }
  ps[g * 64 + p] = s1;
  ps[256 + g * 64 + p] = s2;
  __syncthreads();
  float mu = 0.f, m2 = 0.f;
#pragma unroll
  for (int j = 0; j < 4; j++) {
    mu += ps[j * 64 + p];
    m2 += ps[256 + j * 64 + p];
  }
  mu *= (1.f / 64.f);
  m2 *= (1.f / 64.f);
  float rinv = rsqrtf(m2 - mu * mu + 1e-5f);
#pragma unroll
  for (int i = 0; i < 16; i++) {
    int c = g * 16 + i;
    tn[c * 64 + p] = (xt[c * 64 + p] - mu) * rinv * ln_g[c] + ln_b[c];
  }
  __syncthreads();

  float h[16];
#pragma unroll
  for (int i = 0; i < 16; i++) h[i] = fc1_b[g * 16 + i];
#pragma unroll 4
  for (int c = 0; c < 64; c++) {
    float tv = tn[c * 64 + p];
#pragma unroll
    for (int i = 0; i < 16; i++)
      h[i] = fmaf(tv, fc1_w[(g * 16 + i) * 64 + c], h[i]);
  }
#pragma unroll
  for (int i = 0; i < 16; i++) {
    float z = h[i];
    float u = 0.7978845608028654f * (z + 0.044715f * z * z * z);
    h[i] = 0.5f * z * (1.f + tanhf(u));
  }
#pragma unroll
  for (int i = 0; i < 16; i++) hs[(g * 16 + i) * 64 + p] = h[i];
  __syncthreads();

  float f2[16];
#pragma unroll
  for (int i = 0; i < 16; i++) f2[i] = fc2_b[g * 16 + i];
#pragma unroll 4
  for (int c = 0; c < 64; c++) {
    float hv = hs[c * 64 + p];
#pragma unroll
    for (int i = 0; i < 16; i++)
      f2[i] = fmaf(hv, fc2_w[(g * 16 + i) * 64 + c], f2[i]);
  }
#pragma unroll
  for (int i = 0; i < 16; i++) {
    int c = g * 16 + i;
    x1out[base + (size_t)c * HW + p] = xt[c * 64 + p] + f2[i];
  }
}

extern "C" void kernel_launch(void* const* d_in, const int* in_sizes, int n_in,
                              void* d_out, int out_size, void* d_ws, size_t ws_size,
                              hipStream_t stream) {
  const float* x     = (const float*)d_in[0];
  const float* qk_w  = (const float*)d_in[1];
  const float* v_w   = (const float*)d_in[3];
  const float* v_b   = (const float*)d_in[4];
  const float* out_w = (const float*)d_in[5];
  const float* out_b = (const float*)d_in[6];
  const float* ms1_w = (const float*)d_in[7];
  const float* ms1_b = (const float*)d_in[8];
  const float* ms2_w = (const float*)d_in[9];
  const float* ms2_b = (const float*)d_in[10];
  const float* se1_w = (const float*)d_in[11];
  const float* se1_b = (const float*)d_in[12];
  const float* se2_w = (const float*)d_in[13];
  const float* se2_b = (const float*)d_in[14];
  const float* ln_g  = (const float*)d_in[15];
  const float* ln_b  = (const float*)d_in[16];
  const float* fc1_w = (const float*)d_in[17];
  const float* fc1_b = (const float*)d_in[18];
  const float* fc2_w = (const float*)d_in[19];
  const float* fc2_b = (const float*)d_in[20];
  float* out = (float*)d_out;

  const size_t XCL_BYTES = (size_t)33554432 * 2;  // 64 MB
  const size_t NEED = XCL_BYTES + 4352 +
                      2 * (4096 * 3 + 4096 * 2 + 18432 + 2048);
  int fast = (ws_size >= NEED);

  char* base = (char*)d_ws + (fast ? XCL_BYTES : 0);
  float* gap  = (float*)base;
  float* gate = gap + 512;
  float* ob   = gate + 512;
  unsigned short* tabM  = (unsigned short*)(ob + 64);
  unsigned short* tabWv = tabM + 4096;
  unsigned short* tabWo = tabWv + 4096;
  unsigned short* tabF1 = tabWo + 4096;   // fast path only
  unsigned short* tabF2 = tabF1 + 4096;
  unsigned short* tabW1 = tabF2 + 4096;
  unsigned short* tabW2 = tabW1 + 18432;

  k_prep2<<<113, 256, 0, stream>>>(qk_w, v_w, v_b, out_w, out_b, ms1_w, ms2_w,
                                   fc1_w, fc2_w, tabM, tabWv, tabWo,
                                   fast ? tabF1 : tabM, fast ? tabF2 : tabM,
                                   fast ? tabW1 : tabM, fast ? tabW2 : tabM,
                                   ob, gap, fast);

  if (fast) {
    unsigned short* xcl = (unsigned short*)d_ws;
    k_tocl<<<2048, 256, 0, stream>>>(x, xcl, gap);
    k_ms_mfma<<<dim3(16, 16, 8), 512, 0, stream>>>(x, xcl, tabW1, tabW2,
                                                   ms1_b, ms2_b, out);
    k_attn<<<4096, 512, 0, stream>>>(xcl, tabM, tabWv, tabWo, ob, gap,
                                     se1_w, se1_b, se2_w, se2_b,
                                     ln_g, ln_b, tabF1, fc1_b, tabF2, fc2_b,
                                     out);
  } else {
    k_gap<<<512, 256, 0, stream>>>(x, gap);
    k_gate<<<1, 256, 0, stream>>>(gap, se1_w, se1_b, se2_w, se2_b, gate);
    k_ms_scalar<<<dim3(16, 16, 8), 256, 0, stream>>>(x, ms1_w, ms1_b, ms2_w,
                                                     ms2_b, out);
    k_attn_x<<<8192, 256, 0, stream>>>(x, tabM, tabWv, tabWo, ob, gate, out);
    k_ffn_scalar<<<8192, 256, 0, stream>>>(out, ln_g, ln_b, fc1_w, fc1_b,
                                           fc2_w, fc2_b);
  }
}

// Round 7
// 511.715 us; speedup vs baseline: 1.0144x; 1.0144x over previous
//
#include <hip/hip_runtime.h>
#include <math.h>

#define HW    65536      // 256*256
#define CHW   4194304    // 64*HW
#define SCALE 0.125f

typedef __attribute__((ext_vector_type(8)))  short          bf16x8;
typedef __attribute__((ext_vector_type(4)))  float          f32x4;
typedef __attribute__((ext_vector_type(2)))  unsigned short u16x2;
typedef __attribute__((ext_vector_type(4)))  unsigned short u16x4;
typedef __attribute__((ext_vector_type(8)))  unsigned short u16x8;

#define MFMA(a, b, c) __builtin_amdgcn_mfma_f32_16x16x32_bf16((a), (b), (c), 0, 0, 0)

__device__ __forceinline__ unsigned short f2b(float f) {
  unsigned u = __builtin_bit_cast(unsigned, f);
  return (unsigned short)((u + 0x7fffu + ((u >> 16) & 1u)) >> 16);
}

__device__ __forceinline__ bf16x8 ld_frag(const unsigned short* buf, int tile, int ks,
                                          int ln, int q) {
  return *(const bf16x8*)(buf + (16 * tile + ln) * 72 + 32 * ks + 8 * q);
}

__device__ __forceinline__ void st_cfrag(unsigned short* buf, const f32x4* acc, int wid,
                                         int ln, int q) {
#pragma unroll
  for (int nt = 0; nt < 4; nt++) {
    u16x4 w;
    w[0] = f2b(acc[nt][0]); w[1] = f2b(acc[nt][1]);
    w[2] = f2b(acc[nt][2]); w[3] = f2b(acc[nt][3]);
    *(u16x4*)(buf + (16 * nt + ln) * 72 + 16 * wid + 4 * q) = w;
  }
}

// ---------------- kernel 0: all fragment tables (113 blocks) ----------------
// blk<16 computes M = Qw^T Kw * SCALE and Wvo = Wo.Wv inline (64-FMA dots).
__global__ __launch_bounds__(256) void k_prep2(const float* __restrict__ qk_w,
                                               const float* __restrict__ v_w,
                                               const float* __restrict__ v_b,
                                               const float* __restrict__ out_w,
                                               const float* __restrict__ out_b,
                                               const float* __restrict__ ms1_w,
                                               const float* __restrict__ ms2_w,
                                               const float* __restrict__ fc1_w,
                                               const float* __restrict__ fc2_w,
                                               unsigned short* __restrict__ tabM,
                                               unsigned short* __restrict__ tabWv,
                                               unsigned short* __restrict__ tabWo,
                                               unsigned short* __restrict__ tabWvo,
                                               unsigned short* __restrict__ tabF1,
                                               unsigned short* __restrict__ tabF2,
                                               unsigned short* __restrict__ tabW1,
                                               unsigned short* __restrict__ tabW2,
                                               float* __restrict__ ob,
                                               float* __restrict__ gap,
                                               int build_conv) {
  int blk = blockIdx.x, t = threadIdx.x;
  if (blk < 16) {
    int idx = blk * 256 + t;
    int j = idx & 7, lin = idx >> 3;
    int lane = lin & 63, step = lin >> 6;
    int mt = step >> 1, ks = step & 1, q = lane >> 4, m = lane & 15;
    int k = 32 * ks + 8 * q + j;
    int v = 16 * mt + m;
    float s = 0.f, s2 = 0.f;
    for (int a = 0; a < 64; a++) {
      s  = fmaf(qk_w[a * 64 + k], qk_w[(64 + a) * 64 + v], s);
      s2 = fmaf(out_w[v * 64 + a], v_w[a * 64 + k], s2);
    }
    tabM[idx]   = f2b(s * SCALE);
    tabWv[idx]  = f2b(v_w[v * 64 + k]);
    tabWo[idx]  = f2b(out_w[v * 64 + k]);
    tabWvo[idx] = f2b(s2);
  } else if (blk < 32) {
    if (!build_conv) return;
    int idx = (blk - 16) * 256 + t;
    int j = idx & 7, lin = idx >> 3;
    int lane = lin & 63, step = lin >> 6;
    int mt = step >> 1, ks = step & 1, q = lane >> 4, m = lane & 15;
    int k = 32 * ks + 8 * q + j;
    tabF1[idx] = f2b(fc1_w[(16 * mt + m) * 64 + k]);
    tabF2[idx] = f2b(fc2_w[(16 * mt + m) * 64 + k]);
  } else if (blk < 104) {
    if (!build_conv) return;
    int idx = (blk - 32) * 256 + t;                 // 0..18431
    int j = idx & 7, lane = (idx >> 3) & 63;
    int mt = (idx >> 9) & 1, ks = (idx >> 10) & 1, pos = idx >> 11;
    int o  = 16 * mt + (lane & 15);
    int ci = 32 * ks + 8 * (lane >> 4) + j;
    tabW1[idx] = f2b(ms1_w[(o * 64 + ci) * 9 + pos]);
  } else if (blk < 112) {
    if (!build_conv) return;
    int idx = (blk - 104) * 256 + t;                // 0..2047
    int j = idx & 7, lane = (idx >> 3) & 63, mt = idx >> 9;
    int o = 16 * mt + (lane & 15);
    int k = 8 * (lane >> 4) + j;
    tabW2[idx] = f2b(ms2_w[o * 32 + k]);
  } else {
    if (t < 64) {
      float s = out_b[t];
      for (int c = 0; c < 64; c++) s = fmaf(out_w[t * 64 + c], v_b[c], s);
      ob[t] = s;
    }
    for (int i = t; i < 512; i += 256) gap[i] = 0.f;
  }
}

// ---------------- kernel 0c: x -> channels-last bf16, fused GAP ----------------
__global__ __launch_bounds__(256) void k_tocl(const float* __restrict__ x,
                                              unsigned short* __restrict__ xcl,
                                              float* __restrict__ gap) {
  __shared__ unsigned short tile[16384];   // 256 pix x 64 ch (swizzled chunks)
  __shared__ float wsum[4][64];
  int t = threadIdx.x, lane = t & 63, wid = t >> 6;
  int pid0 = blockIdx.x * 256;
  int b = pid0 >> 16;
  const float* xp = x + (size_t)b * CHW + (pid0 & 65535) + t;
  int sw = t & 7;
#pragma unroll
  for (int c0 = 0; c0 < 8; c0++) {
    float v[8];
#pragma unroll
    for (int i = 0; i < 8; i++) v[i] = xp[(size_t)(c0 * 8 + i) * HW];
    u16x8 w;
#pragma unroll
    for (int i = 0; i < 8; i++) w[i] = f2b(v[i]);
    *(u16x8*)(tile + t * 64 + ((c0 ^ sw) << 3)) = w;
#pragma unroll
    for (int i = 0; i < 8; i++) {
      float s = v[i];
      s += __shfl_xor(s, 1, 64);  s += __shfl_xor(s, 2, 64);
      s += __shfl_xor(s, 4, 64);  s += __shfl_xor(s, 8, 64);
      s += __shfl_xor(s, 16, 64); s += __shfl_xor(s, 32, 64);
      if (lane == 0) wsum[wid][c0 * 8 + i] = s;
    }
  }
  __syncthreads();
  if (t < 64) {
    float g = (wsum[0][t] + wsum[1][t]) + (wsum[2][t] + wsum[3][t]);
    atomicAdd(&gap[b * 64 + t], g);
  }
  unsigned short* op = xcl + (size_t)pid0 * 64;
#pragma unroll
  for (int j = 0; j < 8; j++) {
    int p = j * 32 + (t >> 3);
    bf16x8 v = *(const bf16x8*)(tile + p * 64 + (((t & 7) ^ (p & 7)) << 3));
    *(bf16x8*)(op + j * 2048 + t * 8) = v;   // byte off = j*4096 + t*16: contiguous
  }
}

// ---------------- kernel 1 (fallback): global average pool per (b,c) -------------
__global__ __launch_bounds__(256) void k_gap(const float* __restrict__ x,
                                             float* __restrict__ gap) {
  int bc = blockIdx.x;
  const float4* p4 = (const float4*)(x + (size_t)bc * HW);
  float s = 0.f;
  for (int i = threadIdx.x; i < HW / 4; i += 256) {
    float4 v = p4[i];
    s += (v.x + v.y) + (v.z + v.w);
  }
#pragma unroll
  for (int off = 32; off > 0; off >>= 1) s += __shfl_down(s, off, 64);
  __shared__ float red[4];
  if ((threadIdx.x & 63) == 0) red[threadIdx.x >> 6] = s;
  __syncthreads();
  if (threadIdx.x == 0)
    gap[bc] = (red[0] + red[1] + red[2] + red[3]) * (1.f / 65536.f);
}

// ---------------- kernel 2 (fallback): SE gate ----------------
__global__ __launch_bounds__(256) void k_gate(const float* __restrict__ gap,
                                              const float* __restrict__ se1_w,
                                              const float* __restrict__ se1_b,
                                              const float* __restrict__ se2_w,
                                              const float* __restrict__ se2_b,
                                              float* __restrict__ gate) {
  __shared__ float se[32];
  int t = threadIdx.x;
  if (t < 32) {
    int b = t >> 2, j = t & 3;
    float s = se1_b[j];
    for (int c = 0; c < 64; c++) s = fmaf(gap[b * 64 + c], se1_w[j * 64 + c], s);
    se[t] = fmaxf(s, 0.f);
  }
  __syncthreads();
  for (int i = t; i < 512; i += 256) {
    int b = i >> 6, o = i & 63;
    float s = se2_b[o];
#pragma unroll
    for (int j = 0; j < 4; j++) s = fmaf(se[b * 4 + j], se2_w[o * 4 + j], s);
    gate[i] = 1.f / (1.f + expf(-s));
  }
}

// ---------------- kernel 3 (fast): MFMA conv, 512 threads (8 waves) ----------
__global__ __launch_bounds__(512) void k_ms_mfma(const float* __restrict__ x,
                                                 const unsigned short* __restrict__ xcl,
                                                 const unsigned short* __restrict__ tabW1,
                                                 const unsigned short* __restrict__ tabW2,
                                                 const float* __restrict__ b1,
                                                 const float* __restrict__ b2,
                                                 float* __restrict__ x1) {
  __shared__ unsigned short sX[324 * 72];  // 46656 B; relu buf aliased (256*40 halves)
  int b = blockIdx.z;
  int x0 = blockIdx.x * 16, y0 = blockIdx.y * 16;
  int t = threadIdx.x, lane = t & 63, wid = t >> 6;   // wid 0..7
  int q = lane >> 4, ln = lane & 15;

  for (int i = t; i < 2592; i += 512) {  // 324 pixels x 8 chan-octets
    int c8 = i & 7, pix = i >> 3;
    int yy = pix / 18, xx = pix - yy * 18;
    int gy = y0 + yy - 1, gx = x0 + xx - 1;
    bf16x8 v = {0, 0, 0, 0, 0, 0, 0, 0};
    if (gy >= 0 && gy < 256 && gx >= 0 && gx < 256)
      v = *(const bf16x8*)(xcl + ((size_t)((b << 16) + (gy << 8) + gx) << 6) + c8 * 8);
    *(bf16x8*)(sX + pix * 72 + c8 * 8) = v;
  }
  __syncthreads();

  f32x4 b1v0 = *(const f32x4*)(b1 + 4 * q);
  f32x4 b1v1 = *(const f32x4*)(b1 + 16 + 4 * q);
  f32x4 acc[2][2];
#pragma unroll
  for (int j = 0; j < 2; j++) { acc[j][0] = b1v0; acc[j][1] = b1v1; }

  for (int pos = 0; pos < 9; pos++) {
    int dy = pos / 3, dx = pos - dy * 3;
    bf16x8 A[2][2];
#pragma unroll
    for (int ks = 0; ks < 2; ks++)
#pragma unroll
      for (int mt = 0; mt < 2; mt++)
        A[ks][mt] = *(const bf16x8*)(tabW1 + ((((pos * 2 + ks) * 2 + mt) * 64 + lane) << 3));
#pragma unroll
    for (int j = 0; j < 2; j++) {
      int py = 2 * wid + j;
      int pix = (py + dy) * 18 + ln + dx;
#pragma unroll
      for (int ks = 0; ks < 2; ks++) {
        bf16x8 B = *(const bf16x8*)(sX + pix * 72 + 32 * ks + 8 * q);
        acc[j][0] = MFMA(A[ks][0], B, acc[j][0]);
        acc[j][1] = MFMA(A[ks][1], B, acc[j][1]);
      }
    }
  }
  __syncthreads();  // all conv reads of sX complete

  // relu -> [pix][cin32] pitch 40 halves (aliases sX)
#pragma unroll
  for (int j = 0; j < 2; j++) {
    int pixl = (2 * wid + j) * 16 + ln;
#pragma unroll
    for (int mt = 0; mt < 2; mt++) {
      u16x4 w;
#pragma unroll
      for (int r = 0; r < 4; r++) w[r] = f2b(fmaxf(acc[j][mt][r], 0.f));
      *(u16x4*)(sX + pixl * 40 + 16 * mt + 4 * q) = w;
    }
  }
  __syncthreads();

  bf16x8 A2[4];
#pragma unroll
  for (int mt = 0; mt < 4; mt++)
    A2[mt] = *(const bf16x8*)(tabW2 + ((mt * 64 + lane) << 3));
  f32x4 b2v[4];
#pragma unroll
  for (int mt = 0; mt < 4; mt++) b2v[mt] = *(const f32x4*)(b2 + 16 * mt + 4 * q);

  const f32x4 z4 = {0.f, 0.f, 0.f, 0.f};
#pragma unroll
  for (int j = 0; j < 2; j++) {
    int py = 2 * wid + j;
    bf16x8 B = *(const bf16x8*)(sX + (py * 16 + ln) * 40 + 8 * q);
    f32x4 acc2[4] = {z4, z4, z4, z4};
#pragma unroll
    for (int mt = 0; mt < 4; mt++) acc2[mt] = MFMA(A2[mt], B, acc2[mt]);
    size_t pbase = (size_t)b * CHW + (size_t)(y0 + py) * 256 + x0 + ln;
#pragma unroll
    for (int mt = 0; mt < 4; mt++)
#pragma unroll
      for (int r = 0; r < 4; r++) {
        int o = 16 * mt + 4 * q + r;
        size_t idx = pbase + (size_t)o * HW;
        x1[idx] = x[idx] + acc2[mt][r] + b2v[mt][r];
      }
  }
}

// ---------------- kernel 3 (fallback): scalar conv, same semantics ----------------
__global__ __launch_bounds__(256) void k_ms_scalar(const float* __restrict__ x,
                                                   const float* __restrict__ w1,
                                                   const float* __restrict__ b1,
                                                   const float* __restrict__ w2,
                                                   const float* __restrict__ b2,
                                                   float* __restrict__ x1) {
  int b = blockIdx.z;
  int x0 = blockIdx.x * 16, y0 = blockIdx.y * 16;
  int tx = threadIdx.x & 15, ty = threadIdx.x >> 4;
  __shared__ float xt[16 * 324];
  float acc[32];
#pragma unroll
  for (int o = 0; o < 32; o++) acc[o] = 0.f;
  const float* xb = x + (size_t)b * CHW;

  for (int cc = 0; cc < 64; cc += 16) {
    __syncthreads();
    for (int idx = threadIdx.x; idx < 16 * 324; idx += 256) {
      int ci = idx / 324;
      int rem = idx - ci * 324;
      int yy = rem / 18, xx = rem - yy * 18;
      int gy = y0 + yy - 1, gx = x0 + xx - 1;
      float v = 0.f;
      if (gy >= 0 && gy < 256 && gx >= 0 && gx < 256)
        v = xb[(size_t)(cc + ci) * HW + gy * 256 + gx];
      xt[idx] = v;
    }
    __syncthreads();
    for (int ci = 0; ci < 16; ci++) {
      float xv[9];
#pragma unroll
      for (int dy = 0; dy < 3; dy++)
#pragma unroll
        for (int dx = 0; dx < 3; dx++)
          xv[dy * 3 + dx] = xt[ci * 324 + (ty + dy) * 18 + tx + dx];
      const float* wp = w1 + (size_t)(cc + ci) * 9;
#pragma unroll
      for (int o = 0; o < 32; o++) {
        float s = acc[o];
#pragma unroll
        for (int k = 0; k < 9; k++) s = fmaf(xv[k], wp[o * 576 + k], s);
        acc[o] = s;
      }
    }
  }
  float r[32];
#pragma unroll
  for (int o = 0; o < 32; o++) r[o] = fmaxf(acc[o] + b1[o], 0.f);
  size_t pix = (size_t)(y0 + ty) * 256 + (x0 + tx);
  size_t base = (size_t)b * CHW + pix;
#pragma unroll 8
  for (int o = 0; o < 64; o++) {
    float s = b2[o];
#pragma unroll
    for (int i = 0; i < 32; i++) s = fmaf(r[i], w2[o * 32 + i], s);
    x1[base + (size_t)o * HW] = xb[(size_t)o * HW + pix] + s;
  }
}

// ---------------- kernel 4 (fast): attention + SE + LN + FFN, Wvo-fused -----------
// Out-proj folded into PV via Wvo = Wo.Wv (Y = (Wvo.X).E * inv_tot). Unnormalized
// softmax: E stored raw; 1/tot applied to Y columns. 5 MFMA phases, 9 barriers.
// LN partials live in dead E buffer; {mred, mus/rvs} union in 2KB scratch.
// LDS ~38.9KB -> 4 blocks/CU LDS-cap (occupancy diagnostic).
__global__ __launch_bounds__(512) void k_attn(const unsigned short* __restrict__ xcl,
                                              const unsigned short* __restrict__ tabM,
                                              const unsigned short* __restrict__ tabWvo,
                                              const float* __restrict__ ob,
                                              const float* __restrict__ gap,
                                              const float* __restrict__ se1_w,
                                              const float* __restrict__ se1_b,
                                              const float* __restrict__ se2_w,
                                              const float* __restrict__ se2_b,
                                              const float* __restrict__ ln_g,
                                              const float* __restrict__ ln_b,
                                              const unsigned short* __restrict__ tabF1,
                                              const float* __restrict__ fc1_b,
                                              const unsigned short* __restrict__ tabF2,
                                              const float* __restrict__ fc2_b,
                                              float* __restrict__ x1) {
  __shared__ unsigned short sA[2][4608], sB[2][4608];
  __shared__ float scratch[2][256];     // mred (phase3), then mus[0..63]/rvs[64..127]
  __shared__ float seh[4];
  int n = blockIdx.x;                  // 4096 blocks
  int b = n >> 9, rem = n & 511;
  int wy = rem >> 4, wx2 = rem & 15;
  int t = threadIdx.x;
  int wg = t >> 8;                     // which window half
  int th = t & 255;
  int lane = th & 63, wl = th >> 6;    // role-wave within half
  int q = lane >> 4, ln = lane & 15;
  int wx = wx2 * 2 + wg;
  int pid0 = (b << 16) + ((wy * 8) << 8) + wx * 8;  // pixel id of window origin

  unsigned short* mA = sA[wg];
  unsigned short* mB = sB[wg];
  float* scr = scratch[wg];
  float* pssf = (float*)mB;            // LN partials overlay (E dead by then)

  // ---- load window from xcl: fully coalesced ----
  {
    const unsigned short* xw = xcl + ((size_t)pid0 << 6);
#pragma unroll
    for (int it = 0; it < 2; it++) {
      int id = th + 256 * it;          // 0..511
      int tok = id >> 3, c8 = id & 7;
      int off = ((tok >> 3) << 8) + (tok & 7);  // row*256 + col
      bf16x8 v = *(const bf16x8*)(xw + ((size_t)off << 6) + c8 * 8);
      *(bf16x8*)(mA + tok * 72 + c8 * 8) = v;
    }
  }

  // ---- prefetch x1 residual (x + ms, written by k_ms) ----
  float* x1b = x1 + (size_t)b * CHW + (size_t)(wy * 8) * 256 + wx * 8;
  float xv[4][4];
#pragma unroll
  for (int r = 0; r < 4; r++) {
    int cho = 16 * wl + 4 * q + r;
#pragma unroll
    for (int nt = 0; nt < 4; nt++) {
      int tok = 16 * nt + ln;
      xv[nt][r] = x1b[(size_t)cho * HW + (size_t)(tok >> 3) * 256 + (tok & 7)];
    }
  }

  // ---- SE hidden layer: wave 0, lane-parallel over 64 channels ----
  if (t < 64) {
    float gv = gap[b * 64 + t] * (1.f / 65536.f);
#pragma unroll
    for (int j = 0; j < 4; j++) {
      float p = gv * se1_w[j * 64 + t];
      p += __shfl_xor(p, 1, 64);  p += __shfl_xor(p, 2, 64);
      p += __shfl_xor(p, 4, 64);  p += __shfl_xor(p, 8, 64);
      p += __shfl_xor(p, 16, 64); p += __shfl_xor(p, 32, 64);
      if (t == 0) seh[j] = fmaxf(p + se1_b[j], 0.f);
    }
  }
  __syncthreads();                                          // B1

  const f32x4 z4 = {0.f, 0.f, 0.f, 0.f};

  // ---- phase 1: T = M . X^T -> mB ----
  {
    bf16x8 a0 = *(const bf16x8*)(tabM + ((wl * 2 + 0) * 64 + lane) * 8);
    bf16x8 a1 = *(const bf16x8*)(tabM + ((wl * 2 + 1) * 64 + lane) * 8);
    f32x4 acc[4] = {z4, z4, z4, z4};
#pragma unroll
    for (int nt = 0; nt < 4; nt++) {
      bf16x8 b0 = ld_frag(mA, nt, 0, ln, q);
      bf16x8 b1 = ld_frag(mA, nt, 1, ln, q);
      acc[nt] = MFMA(a0, b0, acc[nt]);
      acc[nt] = MFMA(a1, b1, acc[nt]);
    }
    st_cfrag(mB, acc, wl, ln, q);
  }
  __syncthreads();                                          // B2

  // ---- phase 2: S = X.T^T (scores), VX = (Wvo.X)^T ----
  f32x4 accS[4] = {z4, z4, z4, z4}, accVX[4] = {z4, z4, z4, z4};
  {
    bf16x8 xa0 = ld_frag(mA, wl, 0, ln, q);
    bf16x8 xa1 = ld_frag(mA, wl, 1, ln, q);
#pragma unroll
    for (int nt = 0; nt < 4; nt++) {
      bf16x8 tb0 = ld_frag(mB, nt, 0, ln, q);
      bf16x8 tb1 = ld_frag(mB, nt, 1, ln, q);
      accS[nt] = MFMA(xa0, tb0, accS[nt]);
      accS[nt] = MFMA(xa1, tb1, accS[nt]);
      bf16x8 vb0 = *(const bf16x8*)(tabWvo + ((nt * 2 + 0) * 64 + lane) * 8);
      bf16x8 vb1 = *(const bf16x8*)(tabWvo + ((nt * 2 + 1) * 64 + lane) * 8);
      accVX[nt] = MFMA(xa0, vb0, accVX[nt]);
      accVX[nt] = MFMA(xa1, vb1, accVX[nt]);
    }
  }

  // E = exp(S) + per-column partial sums (registers only)
  float psum[4];
#pragma unroll
  for (int nt = 0; nt < 4; nt++) {
    f32x4 e;
    e[0] = __expf(accS[nt][0]); e[1] = __expf(accS[nt][1]);
    e[2] = __expf(accS[nt][2]); e[3] = __expf(accS[nt][3]);
    accS[nt] = e;
    float s = (e[0] + e[1]) + (e[2] + e[3]);
    s += __shfl_xor(s, 16, 64);
    s += __shfl_xor(s, 32, 64);
    psum[nt] = s;
  }
  __syncthreads();                     // B3: all mA(X)/mB(T) reads complete

  st_cfrag(mA, accVX, wl, ln, q);      // VX overwrites window tile
  st_cfrag(mB, accS, wl, ln, q);       // E (unnormalized) overwrites T
  if (lane < 16) {
#pragma unroll
    for (int nt = 0; nt < 4; nt++) scr[wl * 64 + nt * 16 + ln] = psum[nt];
  }
  __syncthreads();                                          // B4

  // ---- phase 3: Y' = VX . E ; epilogue folds 1/tot, gate, ob ----
  f32x4 accO[4] = {z4, z4, z4, z4};
  {
    bf16x8 va0 = ld_frag(mA, wl, 0, ln, q);
    bf16x8 va1 = ld_frag(mA, wl, 1, ln, q);
#pragma unroll
    for (int nt = 0; nt < 4; nt++) {
      bf16x8 eb0 = ld_frag(mB, nt, 0, ln, q);
      bf16x8 eb1 = ld_frag(mB, nt, 1, ln, q);
      accO[nt] = MFMA(va0, eb0, accO[nt]);
      accO[nt] = MFMA(va1, eb1, accO[nt]);
    }
  }
  float invt[4];
#pragma unroll
  for (int nt = 0; nt < 4; nt++) {
    int col = nt * 16 + ln;
    float tot = (scr[col] + scr[64 + col]) + (scr[128 + col] + scr[192 + col]);
    invt[nt] = 1.f / tot;
  }
#pragma unroll
  for (int r = 0; r < 4; r++) {
    int cho = 16 * wl + 4 * q + r;
    f32x4 w2v = *(const f32x4*)(se2_w + cho * 4);
    float sg = se2_b[cho] + seh[0] * w2v[0] + seh[1] * w2v[1] +
               seh[2] * w2v[2] + seh[3] * w2v[3];
    float gv = 1.f / (1.f + expf(-sg));
    float obg = ob[cho] * gv;
#pragma unroll
    for (int nt = 0; nt < 4; nt++)
      xv[nt][r] = xv[nt][r] + accO[nt][r] * invt[nt] * gv + obg;
  }
  __syncthreads();                     // B5: mB(E)/scr(mred) reads complete

  // ---- LN partials -> pssf (overlay in mB) ----
#pragma unroll
  for (int nt = 0; nt < 4; nt++) {
    float s1 = (xv[nt][0] + xv[nt][1]) + (xv[nt][2] + xv[nt][3]);
    float s2 = fmaf(xv[nt][0], xv[nt][0], xv[nt][1] * xv[nt][1]) +
               fmaf(xv[nt][2], xv[nt][2], xv[nt][3] * xv[nt][3]);
    s1 += __shfl_xor(s1, 16, 64); s1 += __shfl_xor(s1, 32, 64);
    s2 += __shfl_xor(s2, 16, 64); s2 += __shfl_xor(s2, 32, 64);
    if (lane < 16) {
      pssf[wl * 64 + 16 * nt + ln] = s1;
      pssf[256 + wl * 64 + 16 * nt + ln] = s2;
    }
  }
  __syncthreads();                                          // B6

  if (wl == 0) {
    int tok = lane;
    float s1 = (pssf[tok] + pssf[64 + tok]) + (pssf[128 + tok] + pssf[192 + tok]);
    float s2 = (pssf[256 + tok] + pssf[320 + tok]) +
               (pssf[384 + tok] + pssf[448 + tok]);
    float mu = s1 * (1.f / 64.f);
    float m2 = s2 * (1.f / 64.f);
    scr[tok] = mu;                         // mus
    scr[64 + tok] = rsqrtf(m2 - mu * mu + 1e-5f);  // rvs
  }
  __syncthreads();                                          // B7

  // ---- normalized bf16 tile -> mB (overwrites E + pssf) ----
  {
    f32x4 lg = *(const f32x4*)(ln_g + 16 * wl + 4 * q);
    f32x4 lb = *(const f32x4*)(ln_b + 16 * wl + 4 * q);
#pragma unroll
    for (int nt = 0; nt < 4; nt++) {
      int tok = 16 * nt + ln;
      float mu = scr[tok], rinv = scr[64 + tok];
      u16x4 w;
#pragma unroll
      for (int r = 0; r < 4; r++)
        w[r] = f2b((xv[nt][r] - mu) * rinv * lg[r] + lb[r]);
      *(u16x4*)(mB + tok * 72 + 16 * wl + 4 * q) = w;
    }
  }
  __syncthreads();                                          // B8

  // ---- fc1 + GELU -> mA (overwrites VX) ----
  f32x4 accF[4];
  {
    bf16x8 a0 = *(const bf16x8*)(tabF1 + ((wl * 2 + 0) * 64 + lane) * 8);
    bf16x8 a1 = *(const bf16x8*)(tabF1 + ((wl * 2 + 1) * 64 + lane) * 8);
    f32x4 bias1 = *(const f32x4*)(fc1_b + 16 * wl + 4 * q);
#pragma unroll
    for (int nt = 0; nt < 4; nt++) {
      accF[nt] = bias1;
      bf16x8 b0 = ld_frag(mB, nt, 0, ln, q);
      bf16x8 b1 = ld_frag(mB, nt, 1, ln, q);
      accF[nt] = MFMA(a0, b0, accF[nt]);
      accF[nt] = MFMA(a1, b1, accF[nt]);
    }
  }
#pragma unroll
  for (int nt = 0; nt < 4; nt++)
#pragma unroll
    for (int r = 0; r < 4; r++) {
      float z = accF[nt][r];
      float u = 0.7978845608028654f * (z + 0.044715f * z * z * z);
      float e = __expf(-2.f * u);
      accF[nt][r] = z * __builtin_amdgcn_rcpf(1.f + e);
    }
  st_cfrag(mA, accF, wl, ln, q);
  __syncthreads();                                          // B9

  // ---- fc2 + residual write: out = x1 + ffn ----
  {
    bf16x8 c0 = *(const bf16x8*)(tabF2 + ((wl * 2 + 0) * 64 + lane) * 8);
    bf16x8 c1 = *(const bf16x8*)(tabF2 + ((wl * 2 + 1) * 64 + lane) * 8);
    f32x4 bias2 = *(const f32x4*)(fc2_b + 16 * wl + 4 * q);
#pragma unroll
    for (int nt = 0; nt < 4; nt++) {
      f32x4 a2 = bias2;
      bf16x8 b0 = ld_frag(mA, nt, 0, ln, q);
      bf16x8 b1 = ld_frag(mA, nt, 1, ln, q);
      a2 = MFMA(c0, b0, a2);
      a2 = MFMA(c1, b1, a2);
      int tok = 16 * nt + ln;
      size_t rowoff = (size_t)(tok >> 3) * 256 + (tok & 7);
#pragma unroll
      for (int r = 0; r < 4; r++) {
        int cho = 16 * wl + 4 * q + r;
        x1b[(size_t)cho * HW + rowoff] = xv[nt][r] + a2[r];
      }
    }
  }
}

// ---------------- kernel 4 (fallback): original fp32-input attention ----------------
__global__ __launch_bounds__(256) void k_attn_x(const float* __restrict__ x,
                                                const unsigned short* __restrict__ tabM,
                                                const unsigned short* __restrict__ tabWv,
                                                const unsigned short* __restrict__ tabWo,
                                                const float* __restrict__ ob,
                                                const float* __restrict__ gate,
                                                float* __restrict__ x1) {
  __shared__ unsigned short sA[4608], sB[4608], sC[4608];
  __shared__ float red[256];
  int n = blockIdx.x;
  int b = n >> 10, wy = (n >> 5) & 31, wx = n & 31;
  int t = threadIdx.x, lane = t & 63, wid = t >> 6;
  int q = lane >> 4, ln = lane & 15;
  const float* xb = x + (size_t)b * CHW + (size_t)(wy * 8) * 256 + wx * 8;

  {
    int p = t & 31, tg = t >> 5;
    const float* r0 = xb + (size_t)(2 * p) * HW + tg * 256;
    const float* r1 = r0 + HW;
    float a0[8], a1[8];
    *(float4*)&a0[0] = *(const float4*)r0;
    *(float4*)&a0[4] = *(const float4*)(r0 + 4);
    *(float4*)&a1[0] = *(const float4*)r1;
    *(float4*)&a1[4] = *(const float4*)(r1 + 4);
#pragma unroll
    for (int k2 = 0; k2 < 8; k2++) {
      u16x2 w; w[0] = f2b(a0[k2]); w[1] = f2b(a1[k2]);
      *(u16x2*)(sA + (tg * 8 + k2) * 72 + 2 * p) = w;
    }
  }
  __syncthreads();

  const f32x4 z4 = {0.f, 0.f, 0.f, 0.f};

  {
    bf16x8 a0 = *(const bf16x8*)(tabM + ((wid * 2 + 0) * 64 + lane) * 8);
    bf16x8 a1 = *(const bf16x8*)(tabM + ((wid * 2 + 1) * 64 + lane) * 8);
    f32x4 acc[4] = {z4, z4, z4, z4};
#pragma unroll
    for (int nt = 0; nt < 4; nt++) {
      bf16x8 b0 = ld_frag(sA, nt, 0, ln, q);
      bf16x8 b1 = ld_frag(sA, nt, 1, ln, q);
      acc[nt] = MFMA(a0, b0, acc[nt]);
      acc[nt] = MFMA(a1, b1, acc[nt]);
    }
    st_cfrag(sB, acc, wid, ln, q);
  }
  __syncthreads();

  f32x4 accS[4] = {z4, z4, z4, z4}, accV[4] = {z4, z4, z4, z4};
  {
    bf16x8 xa0 = ld_frag(sA, wid, 0, ln, q);
    bf16x8 xa1 = ld_frag(sA, wid, 1, ln, q);
#pragma unroll
    for (int nt = 0; nt < 4; nt++) {
      bf16x8 tb0 = ld_frag(sB, nt, 0, ln, q);
      bf16x8 tb1 = ld_frag(sB, nt, 1, ln, q);
      accS[nt] = MFMA(xa0, tb0, accS[nt]);
      accS[nt] = MFMA(xa1, tb1, accS[nt]);
      bf16x8 vb0 = *(const bf16x8*)(tabWv + ((nt * 2 + 0) * 64 + lane) * 8);
      bf16x8 vb1 = *(const bf16x8*)(tabWv + ((nt * 2 + 1) * 64 + lane) * 8);
      accV[nt] = MFMA(xa0, vb0, accV[nt]);
      accV[nt] = MFMA(xa1, vb1, accV[nt]);
    }
  }
  st_cfrag(sC, accV, wid, ln, q);

  float psum[4];
#pragma unroll
  for (int nt = 0; nt < 4; nt++) {
    f32x4 e;
    e[0] = __expf(accS[nt][0]); e[1] = __expf(accS[nt][1]);
    e[2] = __expf(accS[nt][2]); e[3] = __expf(accS[nt][3]);
    accS[nt] = e;
    float s = (e[0] + e[1]) + (e[2] + e[3]);
    s += __shfl_xor(s, 16, 64);
    s += __shfl_xor(s, 32, 64);
    psum[nt] = s;
  }
  if (lane < 16) {
#pragma unroll
    for (int nt = 0; nt < 4; nt++) red[wid * 64 + nt * 16 + ln] = psum[nt];
  }
  __syncthreads();

  {
    f32x4 accP[4];
#pragma unroll
    for (int nt = 0; nt < 4; nt++) {
      int col = nt * 16 + ln;
      float tot = (red[col] + red[64 + col]) + (red[128 + col] + red[192 + col]);
      float inv = 1.f / tot;
      accP[nt][0] = accS[nt][0] * inv; accP[nt][1] = accS[nt][1] * inv;
      accP[nt][2] = accS[nt][2] * inv; accP[nt][3] = accS[nt][3] * inv;
    }
    st_cfrag(sB, accP, wid, ln, q);
  }
  __syncthreads();

  f32x4 accO[4] = {z4, z4, z4, z4};
  {
    bf16x8 va0 = ld_frag(sC, wid, 0, ln, q);
    bf16x8 va1 = ld_frag(sC, wid, 1, ln, q);
#pragma unroll
    for (int nt = 0; nt < 4; nt++) {
      bf16x8 pb0 = ld_frag(sB, nt, 0, ln, q);
      bf16x8 pb1 = ld_frag(sB, nt, 1, ln, q);
      accO[nt] = MFMA(va0, pb0, accO[nt]);
      accO[nt] = MFMA(va1, pb1, accO[nt]);
    }
  }
  st_cfrag(sA, accO, wid, ln, q);
  __syncthreads();

  f32x4 accY[4] = {z4, z4, z4, z4};
  {
    bf16x8 wa0 = *(const bf16x8*)(tabWo + ((wid * 2 + 0) * 64 + lane) * 8);
    bf16x8 wa1 = *(const bf16x8*)(tabWo + ((wid * 2 + 1) * 64 + lane) * 8);
#pragma unroll
    for (int nt = 0; nt < 4; nt++) {
      bf16x8 ob0 = ld_frag(sA, nt, 0, ln, q);
      bf16x8 ob1 = ld_frag(sA, nt, 1, ln, q);
      accY[nt] = MFMA(wa0, ob0, accY[nt]);
      accY[nt] = MFMA(wa1, ob1, accY[nt]);
    }
  }

  float* x1b = x1 + (size_t)b * CHW + (size_t)(wy * 8) * 256 + wx * 8;
#pragma unroll
  for (int r = 0; r < 4; r++) {
    int cho = 16 * wid + 4 * q + r;
    float gv = gate[b * 64 + cho];
    float obg = ob[cho] * gv;
#pragma unroll
    for (int nt = 0; nt < 4; nt++) {
      int tok = 16 * nt + ln;
      size_t off = (size_t)cho * HW + (size_t)(tok >> 3) * 256 + (tok & 7);
      x1b[off] += accY[nt][r] * gv + obg;
    }
  }
}

// ---------------- kernel 5 (fallback): scalar FFN ----------------
__global__ __launch_bounds__(256) void k_ffn_scalar(float* __restrict__ x1out,
                                                    const float* __restrict__ ln_g,
                                                    const float* __restrict__ ln_b,
                                                    const float* __restrict__ fc1_w,
                                                    const float* __restrict__ fc1_b,
                                                    const float* __restrict__ fc2_w,
                                                    const float* __restrict__ fc2_b) {
  __shared__ float xt[4096], tn[4096], hs[4096], ps[512];
  int n = blockIdx.x;
  int b = n >> 10;
  int rem = n & 1023;
  int y = rem >> 2;
  int x0 = (rem & 3) * 64;
  int t = threadIdx.x, p = t & 63;
  int g = __builtin_amdgcn_readfirstlane(t >> 6);
  size_t base = (size_t)b * CHW + (size_t)y * 256 + x0;

  for (int idx = t; idx < 4096; idx += 256) {
    int c = idx >> 6, pp = idx & 63;
    xt[idx] = x1out[base + (size_t)c * HW + pp];
  }
  __syncthreads();

  float s1 = 0.f, s2 = 0.f;
#pragma unroll
  for (int i = 0; i < 16; i++) {
    float v = xt[(g * 16 + i) * 64 + p];
    s1 += v;
    s2 = fmaf(v, v, s2);
  }
  ps[g * 64 + p] = s1;
  ps[256 + g * 64 + p] = s2;
  __syncthreads();
  float mu = 0.f, m2 = 0.f;
#pragma unroll
  for (int j = 0; j < 4; j++) {
    mu += ps[j * 64 + p];
    m2 += ps[256 + j * 64 + p];
  }
  mu *= (1.f / 64.f);
  m2 *= (1.f / 64.f);
  float rinv = rsqrtf(m2 - mu * mu + 1e-5f);
#pragma unroll
  for (int i = 0; i < 16; i++) {
    int c = g * 16 + i;
    tn[c * 64 + p] = (xt[c * 64 + p] - mu) * rinv * ln_g[c] + ln_b[c];
  }
  __syncthreads();

  float h[16];
#pragma unroll
  for (int i = 0; i < 16; i++) h[i] = fc1_b[g * 16 + i];
#pragma unroll 4
  for (int c = 0; c < 64; c++) {
    float tv = tn[c * 64 + p];
#pragma unroll
    for (int i = 0; i < 16; i++)
      h[i] = fmaf(tv, fc1_w[(g * 16 + i) * 64 + c], h[i]);
  }
#pragma unroll
  for (int i = 0; i < 16; i++) {
    float z = h[i];
    float u = 0.7978845608028654f * (z + 0.044715f * z * z * z);
    h[i] = 0.5f * z * (1.f + tanhf(u));
  }
#pragma unroll
  for (int i = 0; i < 16; i++) hs[(g * 16 + i) * 64 + p] = h[i];
  __syncthreads();

  float f2[16];
#pragma unroll
  for (int i = 0; i < 16; i++) f2[i] = fc2_b[g * 16 + i];
#pragma unroll 4
  for (int c = 0; c < 64; c++) {
    float hv = hs[c * 64 + p];
#pragma unroll
    for (int i = 0; i < 16; i++)
      f2[i] = fmaf(hv, fc2_w[(g * 16 + i) * 64 + c], f2[i]);
  }
#pragma unroll
  for (int i = 0; i < 16; i++) {
    int c = g * 16 + i;
    x1out[base + (size_t)c * HW + p] = xt[c * 64 + p] + f2[i];
  }
}

extern "C" void kernel_launch(void* const* d_in, const int* in_sizes, int n_in,
                              void* d_out, int out_size, void* d_ws, size_t ws_size,
                              hipStream_t stream) {
  const float* x     = (const float*)d_in[0];
  const float* qk_w  = (const float*)d_in[1];
  const float* v_w   = (const float*)d_in[3];
  const float* v_b   = (const float*)d_in[4];
  const float* out_w = (const float*)d_in[5];
  const float* out_b = (const float*)d_in[6];
  const float* ms1_w = (const float*)d_in[7];
  const float* ms1_b = (const float*)d_in[8];
  const float* ms2_w = (const float*)d_in[9];
  const float* ms2_b = (const float*)d_in[10];
  const float* se1_w = (const float*)d_in[11];
  const float* se1_b = (const float*)d_in[12];
  const float* se2_w = (const float*)d_in[13];
  const float* se2_b = (const float*)d_in[14];
  const float* ln_g  = (const float*)d_in[15];
  const float* ln_b  = (const float*)d_in[16];
  const float* fc1_w = (const float*)d_in[17];
  const float* fc1_b = (const float*)d_in[18];
  const float* fc2_w = (const float*)d_in[19];
  const float* fc2_b = (const float*)d_in[20];
  float* out = (float*)d_out;

  const size_t XCL_BYTES = (size_t)33554432 * 2;  // 64 MB
  const size_t NEED = XCL_BYTES + 4352 +
                      2 * (4096 * 6 + 18432 + 2048);
  int fast = (ws_size >= NEED);

  char* base = (char*)d_ws + (fast ? XCL_BYTES : 0);
  float* gap  = (float*)base;
  float* gate = gap + 512;
  float* ob   = gate + 512;
  unsigned short* tabM   = (unsigned short*)(ob + 64);
  unsigned short* tabWv  = tabM + 4096;
  unsigned short* tabWo  = tabWv + 4096;
  unsigned short* tabWvo = tabWo + 4096;
  unsigned short* tabF1  = tabWvo + 4096;  // fast path only
  unsigned short* tabF2  = tabF1 + 4096;
  unsigned short* tabW1  = tabF2 + 4096;
  unsigned short* tabW2  = tabW1 + 18432;

  k_prep2<<<113, 256, 0, stream>>>(qk_w, v_w, v_b, out_w, out_b, ms1_w, ms2_w,
                                   fc1_w, fc2_w, tabM, tabWv, tabWo, tabWvo,
                                   fast ? tabF1 : tabM, fast ? tabF2 : tabM,
                                   fast ? tabW1 : tabM, fast ? tabW2 : tabM,
                                   ob, gap, fast);

  if (fast) {
    unsigned short* xcl = (unsigned short*)d_ws;
    k_tocl<<<2048, 256, 0, stream>>>(x, xcl, gap);
    k_ms_mfma<<<dim3(16, 16, 8), 512, 0, stream>>>(x, xcl, tabW1, tabW2,
                                                   ms1_b, ms2_b, out);
    k_attn<<<4096, 512, 0, stream>>>(xcl, tabM, tabWvo, ob, gap,
                                     se1_w, se1_b, se2_w, se2_b,
                                     ln_g, ln_b, tabF1, fc1_b, tabF2, fc2_b,
                                     out);
  } else {
    k_gap<<<512, 256, 0, stream>>>(x, gap);
    k_gate<<<1, 256, 0, stream>>>(gap, se1_w, se1_b, se2_w, se2_b, gate);
    k_ms_scalar<<<dim3(16, 16, 8), 256, 0, stream>>>(x, ms1_w, ms1_b, ms2_w,
                                                     ms2_b, out);
    k_attn_x<<<8192, 256, 0, stream>>>(x, tabM, tabWv, tabWo, ob, gate, out);
    k_ffn_scalar<<<8192, 256, 0, stream>>>(out, ln_g, ln_b, fc1_w, fc1_b,
                                           fc2_w, fc2_b);
  }
}